// Round 1
// baseline (232.888 us; speedup 1.0000x reference)
//
#include <hip/hip_runtime.h>

#define NUM_SEGS 1024
#define CHUNK_LOG 13
#define CHUNK (1 << CHUNK_LOG)   // 8192 elements per chunk
#define SUBCH 4                  // chunks per block (superchunk = 32768)
#define SUPER (CHUNK * SUBCH)
#define BLK 256

__device__ __forceinline__ float waveReduceSumF(float v) {
#pragma unroll
    for (int off = 32; off > 0; off >>= 1) v += __shfl_down(v, off, 64);
    return v;
}
__device__ __forceinline__ unsigned waveReduceSumU(unsigned v) {
#pragma unroll
    for (int off = 32; off > 0; off >>= 1) v += __shfl_down(v, off, 64);
    return v;
}

// ---------------- init: zero accumulators (ws is poisoned 0xAA every call) ---
__global__ void init_kernel(unsigned* __restrict__ seg_cnt,
                            int* __restrict__ last_idx,
                            unsigned* __restrict__ obs,
                            double* __restrict__ loss1,
                            double* __restrict__ loss2) {
    int t = blockIdx.x * blockDim.x + threadIdx.x;
    if (t < NUM_SEGS) { seg_cnt[t] = 0u; last_idx[t] = -1; }
    if (t == 0) { obs[0] = 0u; loss1[0] = 0.0; loss2[0] = 0.0; }
}

// ---------------- pass 1: chunk exp-sums, per-seg last_idx & count, E stats --
__global__ __launch_bounds__(BLK) void pass1_kernel(
    const float* __restrict__ outs, const int* __restrict__ te,
    const int* __restrict__ tt, int N, int nChunks,
    float* __restrict__ chunk_sums, unsigned* __restrict__ seg_cnt,
    int* __restrict__ last_idx, unsigned* __restrict__ obs,
    double* __restrict__ loss1) {
    __shared__ unsigned hist[NUM_SEGS];
    __shared__ int lmax[NUM_SEGS];
    __shared__ float redF[BLK / 64];
    __shared__ unsigned redU[BLK / 64];

    for (int t = threadIdx.x; t < NUM_SEGS; t += BLK) { hist[t] = 0u; lmax[t] = -1; }
    __syncthreads();

    float sumOE = 0.f;
    unsigned cntE = 0u;
    const int superBase = blockIdx.x * SUPER;
    const int lane = threadIdx.x & 63;
    const int wid = threadIdx.x >> 6;

#pragma unroll 1
    for (int k = 0; k < SUBCH; ++k) {
        const int cbase = superBase + k * CHUNK;
        float sumExp = 0.f;
        if (cbase + CHUNK <= N) {
            // fast path: full chunk, float4/int4 coalesced
#pragma unroll
            for (int it = 0; it < CHUNK / (BLK * 4); ++it) {
                const int i = cbase + it * (BLK * 4) + (threadIdx.x << 2);
                const float4 o = *reinterpret_cast<const float4*>(outs + i);
                const int4 ev = *reinterpret_cast<const int4*>(te + i);
                const int4 sv = *reinterpret_cast<const int4*>(tt + i);
                const float e0 = __expf(o.x), e1 = __expf(o.y);
                const float e2 = __expf(o.z), e3 = __expf(o.w);
                sumExp += (e0 + e1) + (e2 + e3);
                const int s0 = sv.x < 0 ? -sv.x : sv.x;
                const int s1 = sv.y < 0 ? -sv.y : sv.y;
                const int s2 = sv.z < 0 ? -sv.z : sv.z;
                const int s3 = sv.w < 0 ? -sv.w : sv.w;
                atomicMax(&lmax[s0], i);
                atomicMax(&lmax[s1], i + 1);
                atomicMax(&lmax[s2], i + 2);
                atomicMax(&lmax[s3], i + 3);
                if (ev.x > 0) { cntE++; sumOE += o.x; atomicAdd(&hist[s0], 1u); }
                if (ev.y > 0) { cntE++; sumOE += o.y; atomicAdd(&hist[s1], 1u); }
                if (ev.z > 0) { cntE++; sumOE += o.z; atomicAdd(&hist[s2], 1u); }
                if (ev.w > 0) { cntE++; sumOE += o.w; atomicAdd(&hist[s3], 1u); }
            }
        } else {
            // tail path (not hit for N = 16M)
            const int end = (cbase + CHUNK < N) ? cbase + CHUNK : N;
            for (int i = cbase + (int)threadIdx.x; i < end; i += BLK) {
                const float o = outs[i];
                const int e = te[i];
                int s = tt[i]; s = s < 0 ? -s : s;
                sumExp += __expf(o);
                atomicMax(&lmax[s], i);
                if (e > 0) { cntE++; sumOE += o; atomicAdd(&hist[s], 1u); }
            }
        }
        // block-reduce this chunk's exp-sum
        const float w = waveReduceSumF(sumExp);
        if (lane == 0) redF[wid] = w;
        __syncthreads();
        if (threadIdx.x == 0) {
            const float s4 = (redF[0] + redF[1]) + (redF[2] + redF[3]);
            const int cidx = cbase >> CHUNK_LOG;
            if (cidx < nChunks) chunk_sums[cidx] = s4;
        }
        __syncthreads();
    }

    // flush per-block histogram / last-idx to global
    for (int t = threadIdx.x; t < NUM_SEGS; t += BLK) {
        const unsigned h = hist[t];
        if (h) atomicAdd(&seg_cnt[t], h);
        const int m = lmax[t];
        if (m >= 0) atomicMax(&last_idx[t], m);
    }

    // block-reduce E stats
    const float wOE = waveReduceSumF(sumOE);
    const unsigned wC = waveReduceSumU(cntE);
    if (lane == 0) { redF[wid] = wOE; redU[wid] = wC; }
    __syncthreads();
    if (threadIdx.x == 0) {
        const float oe = (redF[0] + redF[1]) + (redF[2] + redF[3]);
        const unsigned c = redU[0] + redU[1] + redU[2] + redU[3];
        atomicAdd(loss1, (double)oe);
        atomicAdd(obs, c);
    }
}

// ---------------- pass 2: exclusive fp64 prefix over chunk sums --------------
__global__ void scan_kernel(const float* __restrict__ csums,
                            double* __restrict__ cprefix, int nChunks) {
    __shared__ double tsum[256];
    const int per = (nChunks + 255) / 256;
    const int start = threadIdx.x * per;
    double s = 0.0;
    for (int j = 0; j < per; ++j) {
        const int c = start + j;
        if (c < nChunks) s += (double)csums[c];
    }
    tsum[threadIdx.x] = s;
    __syncthreads();
    if (threadIdx.x == 0) {
        double acc = 0.0;
        for (int i = 0; i < 256; ++i) { const double t = tsum[i]; tsum[i] = acc; acc += t; }
    }
    __syncthreads();
    double acc = tsum[threadIdx.x];
    for (int j = 0; j < per; ++j) {
        const int c = start + j;
        if (c < nChunks) { cprefix[c] = acc; acc += (double)csums[c]; }
    }
}

// ---------------- pass 3: per-segment seg_max * cnt --------------------------
__global__ __launch_bounds__(256) void seg_kernel(
    const float* __restrict__ outs, const int* __restrict__ last_idx,
    const unsigned* __restrict__ seg_cnt, const double* __restrict__ cprefix,
    double* __restrict__ loss2) {
    __shared__ float redF[4];
    const int t = blockIdx.x;
    const int li = last_idx[t];
    if (li < 0) return;  // empty segment: cnt==0, contributes 0
    const int c = li >> CHUNK_LOG;
    const int base = c << CHUNK_LOG;
    float s = 0.f;
    for (int i = base + (int)threadIdx.x; i <= li; i += 256) s += __expf(outs[i]);
    const float w = waveReduceSumF(s);
    const int lane = threadIdx.x & 63, wid = threadIdx.x >> 6;
    if (lane == 0) redF[wid] = w;
    __syncthreads();
    if (threadIdx.x == 0) {
        const double S = cprefix[c] + (double)((redF[0] + redF[1]) + (redF[2] + redF[3]));
        double sm = log(S);          // monotone cumsum => segment max is at last index
        if (sm < 0.0) sm = 0.0;      // jnp.maximum(..., 0.0)
        atomicAdd(loss2, sm * (double)seg_cnt[t]);
    }
}

// ---------------- finalize ----------------------------------------------------
__global__ void final_kernel(const double* __restrict__ loss1,
                             const double* __restrict__ loss2,
                             const unsigned* __restrict__ obs,
                             float* __restrict__ out) {
    out[0] = (float)((loss2[0] - loss1[0]) / (double)obs[0]);
}

extern "C" void kernel_launch(void* const* d_in, const int* in_sizes, int n_in,
                              void* d_out, int out_size, void* d_ws, size_t ws_size,
                              hipStream_t stream) {
    const float* outs = (const float*)d_in[0];
    const int* te = (const int*)d_in[1];
    const int* tt = (const int*)d_in[2];
    const int N = in_sizes[0];
    float* out = (float*)d_out;

    const int nChunks = (N + CHUNK - 1) / CHUNK;

    char* ws = (char*)d_ws;
    double* d_loss1 = (double*)ws;                       // 1 double
    double* d_loss2 = d_loss1 + 1;                       // 1 double
    double* d_cprefix = (double*)(ws + 16);              // nChunks doubles
    float* d_csums = (float*)(d_cprefix + nChunks);      // nChunks floats
    int* d_lastidx = (int*)(d_csums + nChunks);          // NUM_SEGS ints
    unsigned* d_segcnt = (unsigned*)(d_lastidx + NUM_SEGS);
    unsigned* d_obs = d_segcnt + NUM_SEGS;

    init_kernel<<<(NUM_SEGS + 255) / 256, 256, 0, stream>>>(d_segcnt, d_lastidx,
                                                            d_obs, d_loss1, d_loss2);
    const int nSuper = (N + SUPER - 1) / SUPER;
    pass1_kernel<<<nSuper, BLK, 0, stream>>>(outs, te, tt, N, nChunks, d_csums,
                                             d_segcnt, d_lastidx, d_obs, d_loss1);
    scan_kernel<<<1, 256, 0, stream>>>(d_csums, d_cprefix, nChunks);
    seg_kernel<<<NUM_SEGS, 256, 0, stream>>>(outs, d_lastidx, d_segcnt, d_cprefix,
                                             d_loss2);
    final_kernel<<<1, 1, 0, stream>>>(d_loss1, d_loss2, d_obs, out);
}